// Round 2
// baseline (368.057 us; speedup 1.0000x reference)
//
#include <hip/hip_runtime.h>
#include <stdint.h>

#define EPS_NORM 1e-12f
#define F32_TINY 1.17549435e-38f

// ---------------- Threefry2x32 (exact JAX replica, 20 rounds) ----------------
__device__ __forceinline__ void threefry2x32(uint32_t k0, uint32_t k1,
                                             uint32_t x0, uint32_t x1,
                                             uint32_t& o0, uint32_t& o1) {
  uint32_t ks2 = k0 ^ k1 ^ 0x1BD11BDAu;
  x0 += k0; x1 += k1;
#define TF_ROT(r) { x0 += x1; x1 = (x1 << (r)) | (x1 >> (32 - (r))); x1 ^= x0; }
  TF_ROT(13) TF_ROT(15) TF_ROT(26) TF_ROT(6)
  x0 += k1; x1 += ks2 + 1u;
  TF_ROT(17) TF_ROT(29) TF_ROT(16) TF_ROT(24)
  x0 += ks2; x1 += k0 + 2u;
  TF_ROT(13) TF_ROT(15) TF_ROT(26) TF_ROT(6)
  x0 += k0; x1 += k1 + 3u;
  TF_ROT(17) TF_ROT(29) TF_ROT(16) TF_ROT(24)
  x0 += k1; x1 += ks2 + 4u;
  TF_ROT(13) TF_ROT(15) TF_ROT(26) TF_ROT(6)
  x0 += ks2; x1 += k0 + 5u;
#undef TF_ROT
  o0 = x0; o1 = x1;
}

// ---------------- init: copy kg -> out0 (float) and -> wkg2 (int) ------------
__global__ __launch_bounds__(256) void k_init(const int* __restrict__ kg,
                                              float* __restrict__ out0,
                                              int* __restrict__ wkg2, int n) {
  int i = blockIdx.x * 256 + threadIdx.x;
  if (i < n) { int v = kg[i]; out0[i] = (float)v; wkg2[i] = v; }
}

// ------------- generic 64x64 row transform: out = l2norm(E[g[r]] @ W + b) ----
__global__ __launch_bounds__(256) void k_transform64(
    const float* __restrict__ src, const int* __restrict__ gidx,
    const float* __restrict__ W, const float* __restrict__ bias,
    float* __restrict__ out, int nrows) {
  __shared__ float Wl[4096];
  for (int i = threadIdx.x; i < 4096; i += 256) Wl[i] = W[i];
  __syncthreads();
  int wid = threadIdx.x >> 6, lane = threadIdx.x & 63;
  int row = blockIdx.x * 4 + wid;
  if (row >= nrows) return;
  size_t srow = gidx ? (size_t)gidx[row] : (size_t)row;
  float e = src[srow * 64 + lane];
  float y = 0.f;
#pragma unroll
  for (int k = 0; k < 64; ++k) y = fmaf(__shfl(e, k), Wl[k * 64 + lane], y);
  y += bias[lane];
  float ss = y * y;
#pragma unroll
  for (int off = 32; off; off >>= 1) ss += __shfl_xor(ss, off);
  float yn = y / fmaxf(sqrtf(ss), EPS_NORM);
  out[(size_t)row * 64 + lane] = yn;
}

// ---------------- ui_e = l2norm(concat(U[users], Iemb) @ uiW + uib) ----------
__global__ __launch_bounds__(256) void k_ui(
    const float* __restrict__ U, const int* __restrict__ users,
    const float* __restrict__ Iemb, const float* __restrict__ W,
    const float* __restrict__ bias, float* __restrict__ out, int B) {
  __shared__ float Wl[8192];
  for (int i = threadIdx.x; i < 8192; i += 256) Wl[i] = W[i];
  __syncthreads();
  int wid = threadIdx.x >> 6, lane = threadIdx.x & 63;
  int b = blockIdx.x * 4 + wid;
  if (b >= B) return;
  float u  = U[(size_t)users[b] * 64 + lane];
  float it = Iemb[(size_t)b * 64 + lane];
  float y = 0.f;
#pragma unroll
  for (int k = 0; k < 64; ++k) y = fmaf(__shfl(u, k), Wl[k * 64 + lane], y);
#pragma unroll
  for (int k = 0; k < 64; ++k) y = fmaf(__shfl(it, k), Wl[(64 + k) * 64 + lane], y);
  y += bias[lane];
  float ss = y * y;
#pragma unroll
  for (int off = 32; off; off >>= 1) ss += __shfl_xor(ss, off);
  float yn = y / fmaxf(sqrtf(ss), EPS_NORM);
  out[(size_t)b * 64 + lane] = yn;
}

// ------- step1: fused e1-transform of neighbors + scores + softmax + top4 ----
// One wave per item. lane = output column. W-column lives in 64 VGPRs.
// 4 neighbor rows per pass, embeddings staged TRANSPOSED in LDS so one
// uniform ds_read_b128 broadcasts e[k2] for 4 rows (1 DS-op : 4 FMA).
// All score arithmetic is bitwise-identical to the round-0 version.
__global__ __launch_bounds__(256) void k_score1(
    const int* __restrict__ items, const int* __restrict__ kg,
    const int* __restrict__ nrel, const float* __restrict__ E,
    const float* __restrict__ W1, const float* __restrict__ b1,
    const float* __restrict__ uiE,
    float* __restrict__ out0, float* __restrict__ ap1_out,
    int* __restrict__ s1_idx, int* __restrict__ s1_rel, int* __restrict__ s1_ent,
    float* __restrict__ lmp1) {
  __shared__ float4 eTv[4][64];   // per-wave transposed 4-row tile: [k2].{r0..r3}
  __shared__ float s_sh[4][64];
  int tid = threadIdx.x;
  int wv = tid >> 6, lane = tid & 63;
  int b = blockIdx.x * 4 + wv;
  int item = items[b];
  float ui_l = uiE[(size_t)b * 64 + lane];
  float b1_l = b1[lane];
  float Wreg[64];
#pragma unroll
  for (int k2 = 0; k2 < 64; ++k2) Wreg[k2] = W1[k2 * 64 + lane];
  int nbAll = kg[(size_t)item * 64 + lane];
  float* et = (float*)(&eTv[wv][0]);
  int r = lane >> 4, ci = lane & 15;
  float sc = 0.f;                 // this lane's score (for row == lane)
  for (int g = 0; g < 16; ++g) {
    int nb = __shfl(nbAll, g * 4 + r);
    float4 ev = *reinterpret_cast<const float4*>(E + (size_t)nb * 64 + ci * 4);
    et[(ci * 4 + 0) * 4 + r] = ev.x;
    et[(ci * 4 + 1) * 4 + r] = ev.y;
    et[(ci * 4 + 2) * 4 + r] = ev.z;
    et[(ci * 4 + 3) * 4 + r] = ev.w;
    float ys[4] = {0.f, 0.f, 0.f, 0.f};
#pragma unroll
    for (int k2 = 0; k2 < 64; ++k2) {
      float4 f = eTv[wv][k2];     // uniform addr -> broadcast of 4 rows' e[k2]
      ys[0] = fmaf(f.x, Wreg[k2], ys[0]);
      ys[1] = fmaf(f.y, Wreg[k2], ys[1]);
      ys[2] = fmaf(f.z, Wreg[k2], ys[2]);
      ys[3] = fmaf(f.w, Wreg[k2], ys[3]);
    }
#pragma unroll
    for (int rr = 0; rr < 4; ++rr) {
      float y = ys[rr] + b1_l;
      float ss = y * y;
#pragma unroll
      for (int off = 32; off; off >>= 1) ss += __shfl_xor(ss, off);
      float yn = y / fmaxf(sqrtf(ss), EPS_NORM);
      float d = yn * ui_l;
#pragma unroll
      for (int off = 32; off; off >>= 1) d += __shfl_xor(d, off);
      if (lane == 0) s_sh[wv][g * 4 + rr] = d;
    }
  }
  float s = s_sh[wv][lane];
  // softmax over 64 (identical to round-0)
  float m = s;
#pragma unroll
  for (int off = 32; off; off >>= 1) m = fmaxf(m, __shfl_xor(m, off));
  float ex = expf(s - m);
  float sum = ex;
#pragma unroll
  for (int off = 32; off; off >>= 1) sum += __shfl_xor(sum, off);
  float p = ex / sum;
  // stable descending rank on p (ties -> lower index first), mirrors lax.top_k
  int rank = 0;
  for (int k2 = 0; k2 < 64; ++k2) {
    float pv = __shfl(p, k2);
    rank += (pv > p || (pv == p && k2 < lane)) ? 1 : 0;
  }
  // sum top-4 probs in rank order: ((p0+p1)+p2)+p3
  float acc = 0.f;
#pragma unroll
  for (int rr = 0; rr < 4; ++rr) {
    unsigned long long msk = __ballot(rank == rr);
    int src = __ffsll(msk) - 1;
    acc += __shfl(p, src);
  }
  float lm = logf(acc * 0.25f);
  if (lane == 0) { ap1_out[b] = lm; lmp1[b] = lm; }
  if (rank < 4) {
    s1_idx[b * 4 + rank] = lane;
    s1_ent[b * 4 + rank] = nbAll;
    s1_rel[b * 4 + rank] = nrel[(size_t)item * 64 + lane];
    out0[(size_t)item * 64 + lane] = 0.0f;  // cf_kg1 zero-scatter (all writes 0)
  }
}

// ------- step2a: raw-embedding candidate scores + stable top-32 --------------
__global__ __launch_bounds__(256) void k_score2(
    const int* __restrict__ users, const int* __restrict__ s1_rel,
    const float* __restrict__ U, const float* __restrict__ E,
    const int* __restrict__ allc, int* __restrict__ kept, int N) {
  int wid = threadIdx.x >> 6, lane = threadIdx.x & 63;
  int n = blockIdx.x * 4 + wid;
  if (n >= N) return;
  int b = n >> 2;
  int rel = s1_rel[n];
  int ent = allc[rel * 64 + lane];
  float u = U[(size_t)users[b] * 64 + lane];
  const float4* e4 = reinterpret_cast<const float4*>(E + (size_t)ent * 64);
  float s = 0.f;
#pragma unroll
  for (int j4 = 0; j4 < 16; ++j4) {
    float4 t = e4[j4];
    s = fmaf(__shfl(u, 4 * j4 + 0), t.x, s);
    s = fmaf(__shfl(u, 4 * j4 + 1), t.y, s);
    s = fmaf(__shfl(u, 4 * j4 + 2), t.z, s);
    s = fmaf(__shfl(u, 4 * j4 + 3), t.w, s);
  }
  int rank = 0;
  for (int k2 = 0; k2 < 64; ++k2) {
    float sv = __shfl(s, k2);
    rank += (sv > s || (sv == s && k2 < lane)) ? 1 : 0;
  }
  if (rank < 32) kept[n * 32 + rank] = (lane << 18) | ent;  // pack (col, entity)
}

// ------- step2b: s2, log_softmax, gumbel-argmax sample, scatter --------------
__global__ __launch_bounds__(256) void k_sample(
    const int* __restrict__ items,
    const int* __restrict__ s1_idx, const int* __restrict__ s1_rel,
    const int* __restrict__ s1_ent,
    const float* __restrict__ E, const float* __restrict__ W1,
    const float* __restrict__ b1, const float* __restrict__ T2c,
    const float* __restrict__ uiE, const int* __restrict__ kept,
    float* __restrict__ p2, int* __restrict__ wkg2, int N) {
  __shared__ float Wl[4096];
  int tid = threadIdx.x;
  for (int i = tid; i < 4096; i += 256) Wl[i] = W1[i];
  __syncthreads();
  int wid = tid >> 6, lane = tid & 63;
  int n = blockIdx.x * 4 + wid;
  if (n >= N) return;
  int b = n >> 2;
  int rel = s1_rel[n];
  int repl = s1_ent[n];
  // recompute replaced_e = l2norm(E[repl] @ e1_W + e1_b) (bitwise == k_score1's)
  float e = E[(size_t)repl * 64 + lane];
  float y = 0.f;
#pragma unroll
  for (int k2 = 0; k2 < 64; ++k2) y = fmaf(__shfl(e, k2), Wl[k2 * 64 + lane], y);
  y += b1[lane];
  float ss = y * y;
#pragma unroll
  for (int off = 32; off; off >>= 1) ss += __shfl_xor(ss, off);
  float yn = y / fmaxf(sqrtf(ss), EPS_NORM);
  float q = uiE[(size_t)b * 64 + lane] * yn;   // (ui_rep * replaced_e)[j], j=lane
  int m = lane & 31;                            // both halves mirror m -> no divergence
  int pk = kept[n * 32 + m];
  int c = pk >> 18;
  int ent = pk & 0x3FFFF;
  const float4* c4 = reinterpret_cast<const float4*>(T2c + ((size_t)rel * 64 + c) * 64);
  float s = 0.f;
#pragma unroll
  for (int j4 = 0; j4 < 16; ++j4) {
    float4 t = c4[j4];
    s = fmaf(__shfl(q, 4 * j4 + 0), t.x, s);
    s = fmaf(__shfl(q, 4 * j4 + 1), t.y, s);
    s = fmaf(__shfl(q, 4 * j4 + 2), t.z, s);
    s = fmaf(__shfl(q, 4 * j4 + 3), t.w, s);
  }
  // log_softmax over the 32 distinct values (per-half butterfly)
  float mx = s;
#pragma unroll
  for (int off = 1; off < 32; off <<= 1) mx = fmaxf(mx, __shfl_xor(mx, off));
  float shv = s - mx;
  float se = expf(shv);
  float sum = se;
#pragma unroll
  for (int off = 1; off < 32; off <<= 1) sum += __shfl_xor(sum, off);
  float logp = shv - logf(sum);
  // JAX partitionable threefry gumbel: ctr=(hi=0, lo=flat idx), bits = y0^y1
  uint32_t h0, h1;
  threefry2x32(0u, 42u, 0u, (uint32_t)(n * 32 + m), h0, h1);
  uint32_t bits = h0 ^ h1;
  float u0 = __uint_as_float((bits >> 9) | 0x3F800000u) - 1.0f;
  float uu = fmaxf(u0, F32_TINY);
  float g = -logf(-logf(uu));
  float z = g + logp;
  // stable argmax (ties -> lower index), per-half butterfly
  float bz = z; int bm = m;
#pragma unroll
  for (int off = 1; off < 32; off <<= 1) {
    float oz = __shfl_xor(bz, off);
    int om = __shfl_xor(bm, off);
    if (oz > bz || (oz == bz && om < bm)) { bz = oz; bm = om; }
  }
  if (lane == bm) {  // exactly one lane (lower half)
    p2[n] = expf(logp);
    int col = s1_idx[n];
    int item = items[b];
    atomicMax(&wkg2[(size_t)item * 64 + col], ((b + 1) << 18) | ent);
  }
}

// ---------------- finalize cf_kg2 and ap2 ------------------------------------
__global__ __launch_bounds__(256) void k_final(const int* __restrict__ wkg2,
                                               float* __restrict__ out2, int n) {
  int i = blockIdx.x * 256 + threadIdx.x;
  if (i < n) out2[i] = (float)(wkg2[i] & 0x3FFFF);
}

__global__ __launch_bounds__(256) void k_ap2(const float* __restrict__ p2,
                                             const float* __restrict__ lmp1,
                                             float* __restrict__ out3, int B) {
  int b = blockIdx.x * 256 + threadIdx.x;
  if (b >= B) return;
  float a = ((p2[b * 4] + p2[b * 4 + 1]) + p2[b * 4 + 2]) + p2[b * 4 + 3];
  out3[b] = lmp1[b] + logf(a * 0.25f);
}

// -----------------------------------------------------------------------------
extern "C" void kernel_launch(void* const* d_in, const int* in_sizes, int n_in,
                              void* d_out, int out_size, void* d_ws, size_t ws_size,
                              hipStream_t stream) {
  const int*   users = (const int*)d_in[0];
  const int*   items = (const int*)d_in[1];
  const int*   kg    = (const int*)d_in[2];
  const int*   allc  = (const int*)d_in[3];
  const int*   nrel  = (const int*)d_in[4];
  const float* U     = (const float*)d_in[5];
  const float* E     = (const float*)d_in[6];
  const float* Iemb  = (const float*)d_in[7];
  const float* uiW   = (const float*)d_in[8];
  const float* uib   = (const float*)d_in[9];
  const float* e1W   = (const float*)d_in[10];
  const float* e1b   = (const float*)d_in[11];
  const float* e2W   = (const float*)d_in[12];
  const float* e2b   = (const float*)d_in[13];

  const int B = 4096, NCELL = 3200000, NCAND = 6400, NR4 = 16384;

  float* out0    = (float*)d_out;        // cf_kg1 [3.2M]
  float* out_ap1 = out0 + NCELL;         // ap1    [4096]
  float* out2    = out_ap1 + B;          // cf_kg2 [3.2M]
  float* out_ap2 = out2 + NCELL;         // ap2    [4096]

  float* T2c  = (float*)d_ws;            // 409,600 f
  float* uiE  = T2c + 409600;            // 262,144 f
  int*   wkg2 = (int*)(uiE + 262144);    // 3,200,000 i
  int*   s1i  = wkg2 + NCELL;            // 16384
  int*   s1r  = s1i + NR4;               // 16384
  int*   s1e  = s1r + NR4;               // 16384
  int*   kept = s1e + NR4;               // 524,288
  float* p2   = (float*)(kept + 524288); // 16384
  float* lmp1 = p2 + NR4;                // 4096

  k_init<<<(NCELL + 255) / 256, 256, 0, stream>>>(kg, out0, wkg2, NCELL);
  k_transform64<<<(NCAND + 3) / 4, 256, 0, stream>>>(E, allc, e2W, e2b, T2c, NCAND);
  k_ui<<<(B + 3) / 4, 256, 0, stream>>>(U, users, Iemb, uiW, uib, uiE, B);
  k_score1<<<B / 4, 256, 0, stream>>>(items, kg, nrel, E, e1W, e1b, uiE,
                                      out0, out_ap1, s1i, s1r, s1e, lmp1);
  k_score2<<<(NR4 + 3) / 4, 256, 0, stream>>>(users, s1r, U, E, allc, kept, NR4);
  k_sample<<<(NR4 + 3) / 4, 256, 0, stream>>>(items, s1i, s1r, s1e, E, e1W, e1b,
                                              T2c, uiE, kept, p2, wkg2, NR4);
  k_final<<<(NCELL + 255) / 256, 256, 0, stream>>>(wkg2, out2, NCELL);
  k_ap2<<<(B + 255) / 256, 256, 0, stream>>>(p2, lmp1, out_ap2, B);
}

// Round 3
// 168.271 us; speedup vs baseline: 2.1873x; 2.1873x over previous
//
#include <hip/hip_runtime.h>
#include <stdint.h>

#define EPS_NORM 1e-12f
#define F32_TINY 1.17549435e-38f

static __device__ __forceinline__ int rfl(int v) {
  return __builtin_amdgcn_readfirstlane(v);
}

// ---------------- Threefry2x32 (exact JAX replica, 20 rounds) ----------------
__device__ __forceinline__ void threefry2x32(uint32_t k0, uint32_t k1,
                                             uint32_t x0, uint32_t x1,
                                             uint32_t& o0, uint32_t& o1) {
  uint32_t ks2 = k0 ^ k1 ^ 0x1BD11BDAu;
  x0 += k0; x1 += k1;
#define TF_ROT(r) { x0 += x1; x1 = (x1 << (r)) | (x1 >> (32 - (r))); x1 ^= x0; }
  TF_ROT(13) TF_ROT(15) TF_ROT(26) TF_ROT(6)
  x0 += k1; x1 += ks2 + 1u;
  TF_ROT(17) TF_ROT(29) TF_ROT(16) TF_ROT(24)
  x0 += ks2; x1 += k0 + 2u;
  TF_ROT(13) TF_ROT(15) TF_ROT(26) TF_ROT(6)
  x0 += k0; x1 += k1 + 3u;
  TF_ROT(17) TF_ROT(29) TF_ROT(16) TF_ROT(24)
  x0 += k1; x1 += ks2 + 4u;
  TF_ROT(13) TF_ROT(15) TF_ROT(26) TF_ROT(6)
  x0 += ks2; x1 += k0 + 5u;
#undef TF_ROT
  o0 = x0; o1 = x1;
}

// ---------------- init: copy kg -> out0 (float) and -> wkg2 (int) ------------
__global__ __launch_bounds__(256) void k_init(const int* __restrict__ kg,
                                              float* __restrict__ out0,
                                              int* __restrict__ wkg2, int n) {
  int i = blockIdx.x * 256 + threadIdx.x;
  if (i < n) { int v = kg[i]; out0[i] = (float)v; wkg2[i] = v; }
}

// ------------- generic 64x64 row transform: out = l2norm(E[g[r]] @ W + b) ----
// Row elements are wave-uniform -> scalar loads; W per-lane from LDS.
__global__ __launch_bounds__(256) void k_transform64(
    const float* __restrict__ src, const int* __restrict__ gidx,
    const float* __restrict__ W, const float* __restrict__ bias,
    float* __restrict__ out, int nrows) {
  __shared__ float Wl[4096];
  for (int i = threadIdx.x; i < 4096; i += 256) Wl[i] = W[i];
  __syncthreads();
  int wid = threadIdx.x >> 6, lane = threadIdx.x & 63;
  int row = rfl(blockIdx.x * 4 + wid);
  if (row >= nrows) return;
  int srow = rfl(gidx ? gidx[row] : row);
  const float* er = src + (size_t)srow * 64;
  float y = 0.f;
#pragma unroll
  for (int k = 0; k < 64; ++k) y = fmaf(er[k], Wl[k * 64 + lane], y);
  y += bias[lane];
  float ss = y * y;
#pragma unroll
  for (int off = 32; off; off >>= 1) ss += __shfl_xor(ss, off);
  float yn = y / fmaxf(sqrtf(ss), EPS_NORM);
  out[(size_t)row * 64 + lane] = yn;
}

// ---------------- ui_e = l2norm(concat(U[users], Iemb) @ uiW + uib) ----------
__global__ __launch_bounds__(256) void k_ui(
    const float* __restrict__ U, const int* __restrict__ users,
    const float* __restrict__ Iemb, const float* __restrict__ W,
    const float* __restrict__ bias, float* __restrict__ out, int B) {
  __shared__ float Wl[8192];
  for (int i = threadIdx.x; i < 8192; i += 256) Wl[i] = W[i];
  __syncthreads();
  int wid = threadIdx.x >> 6, lane = threadIdx.x & 63;
  int b = rfl(blockIdx.x * 4 + wid);
  if (b >= B) return;
  int usr = rfl(users[b]);
  const float* ur = U + (size_t)usr * 64;
  const float* ir = Iemb + (size_t)b * 64;
  float y = 0.f;
#pragma unroll
  for (int k = 0; k < 64; ++k) y = fmaf(ur[k], Wl[k * 64 + lane], y);
#pragma unroll
  for (int k = 0; k < 64; ++k) y = fmaf(ir[k], Wl[(64 + k) * 64 + lane], y);
  y += bias[lane];
  float ss = y * y;
#pragma unroll
  for (int off = 32; off; off >>= 1) ss += __shfl_xor(ss, off);
  float yn = y / fmaxf(sqrtf(ss), EPS_NORM);
  out[(size_t)b * 64 + lane] = yn;
}

// ------- step1: fused e1-transform of neighbors + scores + softmax + top4 ----
// lane = neighbor row. y[64] in registers; W/bias/ui wave-uniform (scalar pipe);
// E row per-lane VMEM with 4-deep chunk prefetch. No LDS, no shuffles in the
// matmul. Cross-lane reductions of the reference are replicated in-register as
// exact pairwise trees (fp add commutativity => bitwise identical).
__global__ __launch_bounds__(256) void k_score1(
    const int* __restrict__ items, const int* __restrict__ kg,
    const int* __restrict__ nrel, const float* __restrict__ E,
    const float* __restrict__ W1, const float* __restrict__ b1,
    const float* __restrict__ uiE,
    float* __restrict__ out0, float* __restrict__ ap1_out,
    int* __restrict__ s1_idx, int* __restrict__ s1_rel, int* __restrict__ s1_ent,
    float* __restrict__ lmp1) {
  int tid = threadIdx.x;
  int wv = tid >> 6, lane = tid & 63;
  int b = rfl(blockIdx.x * 4 + wv);
  int item = rfl(items[b]);
  int nb = kg[(size_t)item * 64 + lane];          // this lane's neighbor entity
  const float4* Er = reinterpret_cast<const float4*>(E + (size_t)nb * 64);

  float y[64];
#pragma unroll
  for (int j = 0; j < 64; ++j) y[j] = 0.f;

  float4 c0 = Er[0], c1 = Er[1], c2 = Er[2], c3 = Er[3];
#pragma unroll 1
  for (int cc = 0; cc < 4; ++cc) {
    float4 n0, n1, n2, n3;
    if (cc < 3) { n0 = Er[cc * 4 + 4]; n1 = Er[cc * 4 + 5];
                  n2 = Er[cc * 4 + 6]; n3 = Er[cc * 4 + 7]; }
    float ev[16] = {c0.x, c0.y, c0.z, c0.w, c1.x, c1.y, c1.z, c1.w,
                    c2.x, c2.y, c2.z, c2.w, c3.x, c3.y, c3.z, c3.w};
#pragma unroll
    for (int k2i = 0; k2i < 16; ++k2i) {
      const float4* Wr = reinterpret_cast<const float4*>(
          W1 + ((size_t)(cc * 16 + k2i)) * 64);
      float ek = ev[k2i];
#pragma unroll
      for (int j4 = 0; j4 < 16; ++j4) {
        float4 w = Wr[j4];
        y[j4 * 4 + 0] = fmaf(ek, w.x, y[j4 * 4 + 0]);
        y[j4 * 4 + 1] = fmaf(ek, w.y, y[j4 * 4 + 1]);
        y[j4 * 4 + 2] = fmaf(ek, w.z, y[j4 * 4 + 2]);
        y[j4 * 4 + 3] = fmaf(ek, w.w, y[j4 * 4 + 3]);
      }
    }
    c0 = n0; c1 = n1; c2 = n2; c3 = n3;
  }

  // + bias (wave-uniform)
  const float4* B4 = reinterpret_cast<const float4*>(b1);
#pragma unroll
  for (int j4 = 0; j4 < 16; ++j4) {
    float4 bb = B4[j4];
    float bv[4] = {bb.x, bb.y, bb.z, bb.w};
#pragma unroll
    for (int t = 0; t < 4; ++t) y[j4 * 4 + t] = __fadd_rn(y[j4 * 4 + t], bv[t]);
  }

  // ss = butterfly tree over j (exact replica of shfl_xor 32,16,8,4,2,1)
  float S1[32];
#pragma unroll
  for (int i = 0; i < 32; ++i)
    S1[i] = __fadd_rn(__fmul_rn(y[i], y[i]), __fmul_rn(y[i + 32], y[i + 32]));
#pragma unroll
  for (int i = 0; i < 16; ++i) S1[i] = __fadd_rn(S1[i], S1[i + 16]);
#pragma unroll
  for (int i = 0; i < 8; ++i)  S1[i] = __fadd_rn(S1[i], S1[i + 8]);
#pragma unroll
  for (int i = 0; i < 4; ++i)  S1[i] = __fadd_rn(S1[i], S1[i + 4]);
#pragma unroll
  for (int i = 0; i < 2; ++i)  S1[i] = __fadd_rn(S1[i], S1[i + 2]);
  float ss = __fadd_rn(S1[0], S1[1]);
  float denom = fmaxf(sqrtf(ss), EPS_NORM);

  // s = butterfly tree over j of (y[j]/denom)*ui[j]  (ui wave-uniform)
  const float4* Ur = reinterpret_cast<const float4*>(uiE + (size_t)b * 64);
  float D[32];
#pragma unroll
  for (int i4 = 0; i4 < 8; ++i4) {
    float4 ua = Ur[i4], ub = Ur[i4 + 8];
    float uav[4] = {ua.x, ua.y, ua.z, ua.w};
    float ubv[4] = {ub.x, ub.y, ub.z, ub.w};
#pragma unroll
    for (int t = 0; t < 4; ++t) {
      int i = i4 * 4 + t;
      D[i] = __fadd_rn(__fmul_rn(y[i] / denom, uav[t]),
                       __fmul_rn(y[i + 32] / denom, ubv[t]));
    }
  }
#pragma unroll
  for (int i = 0; i < 16; ++i) D[i] = __fadd_rn(D[i], D[i + 16]);
#pragma unroll
  for (int i = 0; i < 8; ++i)  D[i] = __fadd_rn(D[i], D[i + 8]);
#pragma unroll
  for (int i = 0; i < 4; ++i)  D[i] = __fadd_rn(D[i], D[i + 4]);
#pragma unroll
  for (int i = 0; i < 2; ++i)  D[i] = __fadd_rn(D[i], D[i + 2]);
  float s = __fadd_rn(D[0], D[1]);   // scores1[b, lane]

  // softmax over 64 (verbatim)
  float m = s;
#pragma unroll
  for (int off = 32; off; off >>= 1) m = fmaxf(m, __shfl_xor(m, off));
  float ex = expf(s - m);
  float sum = ex;
#pragma unroll
  for (int off = 32; off; off >>= 1) sum += __shfl_xor(sum, off);
  float p = ex / sum;
  // stable descending rank (ties -> lower index), mirrors lax.top_k
  int rank = 0;
  for (int k2 = 0; k2 < 64; ++k2) {
    float pv = __shfl(p, k2);
    rank += (pv > p || (pv == p && k2 < lane)) ? 1 : 0;
  }
  float acc = 0.f;
#pragma unroll
  for (int rr = 0; rr < 4; ++rr) {
    unsigned long long msk = __ballot(rank == rr);
    int src = __ffsll(msk) - 1;
    acc += __shfl(p, src);
  }
  float lm = logf(acc * 0.25f);
  if (lane == 0) { ap1_out[b] = lm; lmp1[b] = lm; }
  if (rank < 4) {
    s1_idx[b * 4 + rank] = lane;
    s1_ent[b * 4 + rank] = nb;
    s1_rel[b * 4 + rank] = nrel[(size_t)item * 64 + lane];
    out0[(size_t)item * 64 + lane] = 0.0f;  // cf_kg1 zero-scatter
  }
}

// ------- step2a: raw-embedding candidate scores + stable top-32 --------------
__global__ __launch_bounds__(256) void k_score2(
    const int* __restrict__ users, const int* __restrict__ s1_rel,
    const float* __restrict__ U, const float* __restrict__ E,
    const int* __restrict__ allc, int* __restrict__ kept, int N) {
  int wid = threadIdx.x >> 6, lane = threadIdx.x & 63;
  int n = rfl(blockIdx.x * 4 + wid);
  if (n >= N) return;
  int b = n >> 2;
  int rel = rfl(s1_rel[n]);
  int usr = rfl(users[b]);
  int ent = allc[rel * 64 + lane];
  const float* ur = U + (size_t)usr * 64;        // wave-uniform row
  const float4* e4 = reinterpret_cast<const float4*>(E + (size_t)ent * 64);
  float s = 0.f;
#pragma unroll
  for (int j4 = 0; j4 < 16; ++j4) {
    float4 t = e4[j4];
    s = fmaf(ur[4 * j4 + 0], t.x, s);
    s = fmaf(ur[4 * j4 + 1], t.y, s);
    s = fmaf(ur[4 * j4 + 2], t.z, s);
    s = fmaf(ur[4 * j4 + 3], t.w, s);
  }
  int rank = 0;
  for (int k2 = 0; k2 < 64; ++k2) {
    float sv = __shfl(s, k2);
    rank += (sv > s || (sv == s && k2 < lane)) ? 1 : 0;
  }
  if (rank < 32) kept[n * 32 + rank] = (lane << 18) | ent;  // pack (col, entity)
}

// ------- step2b: s2, log_softmax, gumbel-argmax sample, scatter --------------
__global__ __launch_bounds__(256) void k_sample(
    const int* __restrict__ items,
    const int* __restrict__ s1_idx, const int* __restrict__ s1_rel,
    const int* __restrict__ s1_ent,
    const float* __restrict__ E, const float* __restrict__ W1,
    const float* __restrict__ b1, const float* __restrict__ T2c,
    const float* __restrict__ uiE, const int* __restrict__ kept,
    float* __restrict__ p2, int* __restrict__ wkg2, int N) {
  __shared__ float Wl[4096];
  int tid = threadIdx.x;
  for (int i = tid; i < 4096; i += 256) Wl[i] = W1[i];
  __syncthreads();
  int wid = tid >> 6, lane = tid & 63;
  int n = rfl(blockIdx.x * 4 + wid);
  if (n >= N) return;
  int b = n >> 2;
  int rel = rfl(s1_rel[n]);
  int repl = rfl(s1_ent[n]);
  // replaced_e = l2norm(E[repl] @ e1_W + e1_b); row is wave-uniform
  const float* er = E + (size_t)repl * 64;
  float y = 0.f;
#pragma unroll
  for (int k2 = 0; k2 < 64; ++k2) y = fmaf(er[k2], Wl[k2 * 64 + lane], y);
  y += b1[lane];
  float ss = y * y;
#pragma unroll
  for (int off = 32; off; off >>= 1) ss += __shfl_xor(ss, off);
  float yn = y / fmaxf(sqrtf(ss), EPS_NORM);
  float q = uiE[(size_t)b * 64 + lane] * yn;   // (ui_rep * replaced_e)[lane]
  int m = lane & 31;                            // both halves mirror m
  int pk = kept[n * 32 + m];
  int c = pk >> 18;
  int ent = pk & 0x3FFFF;
  const float4* c4 = reinterpret_cast<const float4*>(T2c + ((size_t)rel * 64 + c) * 64);
  float s = 0.f;
#pragma unroll
  for (int j4 = 0; j4 < 16; ++j4) {
    float4 t = c4[j4];
    s = fmaf(__shfl(q, 4 * j4 + 0), t.x, s);
    s = fmaf(__shfl(q, 4 * j4 + 1), t.y, s);
    s = fmaf(__shfl(q, 4 * j4 + 2), t.z, s);
    s = fmaf(__shfl(q, 4 * j4 + 3), t.w, s);
  }
  // log_softmax over the 32 distinct values (per-half butterfly)
  float mx = s;
#pragma unroll
  for (int off = 1; off < 32; off <<= 1) mx = fmaxf(mx, __shfl_xor(mx, off));
  float shv = s - mx;
  float se = expf(shv);
  float sum = se;
#pragma unroll
  for (int off = 1; off < 32; off <<= 1) sum += __shfl_xor(sum, off);
  float logp = shv - logf(sum);
  // JAX partitionable threefry gumbel: ctr=(hi=0, lo=flat idx), bits = y0^y1
  uint32_t h0, h1;
  threefry2x32(0u, 42u, 0u, (uint32_t)(n * 32 + m), h0, h1);
  uint32_t bits = h0 ^ h1;
  float u0 = __uint_as_float((bits >> 9) | 0x3F800000u) - 1.0f;
  float uu = fmaxf(u0, F32_TINY);
  float g = -logf(-logf(uu));
  float z = g + logp;
  // stable argmax (ties -> lower index), per-half butterfly
  float bz = z; int bm = m;
#pragma unroll
  for (int off = 1; off < 32; off <<= 1) {
    float oz = __shfl_xor(bz, off);
    int om = __shfl_xor(bm, off);
    if (oz > bz || (oz == bz && om < bm)) { bz = oz; bm = om; }
  }
  if (lane == bm) {  // exactly one lane (lower half)
    p2[n] = expf(logp);
    int col = s1_idx[n];
    int item = items[b];
    atomicMax(&wkg2[(size_t)item * 64 + col], ((b + 1) << 18) | ent);
  }
}

// ---------------- finalize cf_kg2 and ap2 ------------------------------------
__global__ __launch_bounds__(256) void k_final(const int* __restrict__ wkg2,
                                               float* __restrict__ out2, int n) {
  int i = blockIdx.x * 256 + threadIdx.x;
  if (i < n) out2[i] = (float)(wkg2[i] & 0x3FFFF);
}

__global__ __launch_bounds__(256) void k_ap2(const float* __restrict__ p2,
                                             const float* __restrict__ lmp1,
                                             float* __restrict__ out3, int B) {
  int b = blockIdx.x * 256 + threadIdx.x;
  if (b >= B) return;
  float a = ((p2[b * 4] + p2[b * 4 + 1]) + p2[b * 4 + 2]) + p2[b * 4 + 3];
  out3[b] = lmp1[b] + logf(a * 0.25f);
}

// -----------------------------------------------------------------------------
extern "C" void kernel_launch(void* const* d_in, const int* in_sizes, int n_in,
                              void* d_out, int out_size, void* d_ws, size_t ws_size,
                              hipStream_t stream) {
  const int*   users = (const int*)d_in[0];
  const int*   items = (const int*)d_in[1];
  const int*   kg    = (const int*)d_in[2];
  const int*   allc  = (const int*)d_in[3];
  const int*   nrel  = (const int*)d_in[4];
  const float* U     = (const float*)d_in[5];
  const float* E     = (const float*)d_in[6];
  const float* Iemb  = (const float*)d_in[7];
  const float* uiW   = (const float*)d_in[8];
  const float* uib   = (const float*)d_in[9];
  const float* e1W   = (const float*)d_in[10];
  const float* e1b   = (const float*)d_in[11];
  const float* e2W   = (const float*)d_in[12];
  const float* e2b   = (const float*)d_in[13];

  const int B = 4096, NCELL = 3200000, NCAND = 6400, NR4 = 16384;

  float* out0    = (float*)d_out;        // cf_kg1 [3.2M]
  float* out_ap1 = out0 + NCELL;         // ap1    [4096]
  float* out2    = out_ap1 + B;          // cf_kg2 [3.2M]
  float* out_ap2 = out2 + NCELL;         // ap2    [4096]

  float* T2c  = (float*)d_ws;            // 409,600 f
  float* uiE  = T2c + 409600;            // 262,144 f
  int*   wkg2 = (int*)(uiE + 262144);    // 3,200,000 i
  int*   s1i  = wkg2 + NCELL;            // 16384
  int*   s1r  = s1i + NR4;               // 16384
  int*   s1e  = s1r + NR4;               // 16384
  int*   kept = s1e + NR4;               // 524,288
  float* p2   = (float*)(kept + 524288); // 16384
  float* lmp1 = p2 + NR4;                // 4096

  k_init<<<(NCELL + 255) / 256, 256, 0, stream>>>(kg, out0, wkg2, NCELL);
  k_transform64<<<(NCAND + 3) / 4, 256, 0, stream>>>(E, allc, e2W, e2b, T2c, NCAND);
  k_ui<<<(B + 3) / 4, 256, 0, stream>>>(U, users, Iemb, uiW, uib, uiE, B);
  k_score1<<<B / 4, 256, 0, stream>>>(items, kg, nrel, E, e1W, e1b, uiE,
                                      out0, out_ap1, s1i, s1r, s1e, lmp1);
  k_score2<<<(NR4 + 3) / 4, 256, 0, stream>>>(users, s1r, U, E, allc, kept, NR4);
  k_sample<<<(NR4 + 3) / 4, 256, 0, stream>>>(items, s1i, s1r, s1e, E, e1W, e1b,
                                              T2c, uiE, kept, p2, wkg2, NR4);
  k_final<<<(NCELL + 255) / 256, 256, 0, stream>>>(wkg2, out2, NCELL);
  k_ap2<<<(B + 255) / 256, 256, 0, stream>>>(p2, lmp1, out_ap2, B);
}

// Round 4
// 158.574 us; speedup vs baseline: 2.3210x; 1.0612x over previous
//
#include <hip/hip_runtime.h>
#include <stdint.h>

#define EPS_NORM 1e-12f
#define F32_TINY 1.17549435e-38f

static __device__ __forceinline__ int rfl(int v) {
  return __builtin_amdgcn_readfirstlane(v);
}

// ---------------- Threefry2x32 (exact JAX replica, 20 rounds) ----------------
__device__ __forceinline__ void threefry2x32(uint32_t k0, uint32_t k1,
                                             uint32_t x0, uint32_t x1,
                                             uint32_t& o0, uint32_t& o1) {
  uint32_t ks2 = k0 ^ k1 ^ 0x1BD11BDAu;
  x0 += k0; x1 += k1;
#define TF_ROT(r) { x0 += x1; x1 = (x1 << (r)) | (x1 >> (32 - (r))); x1 ^= x0; }
  TF_ROT(13) TF_ROT(15) TF_ROT(26) TF_ROT(6)
  x0 += k1; x1 += ks2 + 1u;
  TF_ROT(17) TF_ROT(29) TF_ROT(16) TF_ROT(24)
  x0 += ks2; x1 += k0 + 2u;
  TF_ROT(13) TF_ROT(15) TF_ROT(26) TF_ROT(6)
  x0 += k0; x1 += k1 + 3u;
  TF_ROT(17) TF_ROT(29) TF_ROT(16) TF_ROT(24)
  x0 += k1; x1 += ks2 + 4u;
  TF_ROT(13) TF_ROT(15) TF_ROT(26) TF_ROT(6)
  x0 += ks2; x1 += k0 + 5u;
#undef TF_ROT
  o0 = x0; o1 = x1;
}

// ---------------- init: copy kg -> out0 (float) and -> wkg2 (int) ------------
__global__ __launch_bounds__(256) void k_init(const int* __restrict__ kg,
                                              float* __restrict__ out0,
                                              int* __restrict__ wkg2, int n) {
  int i = blockIdx.x * 256 + threadIdx.x;
  if (i < n) { int v = kg[i]; out0[i] = (float)v; wkg2[i] = v; }
}

// ===================== shared transform body (lane = row) ====================
// y[64] accumulators per lane; W/bias wave-uniform (scalar pipe); E row
// per-lane VMEM. Ascending-k fmaf chain + exact butterfly-replica trees.
__device__ __forceinline__ void transform_row(const float4* __restrict__ Er,
                                              const float* __restrict__ W,
                                              const float* __restrict__ bias,
                                              float (&yn)[64]) {
  float y[64];
#pragma unroll
  for (int j = 0; j < 64; ++j) y[j] = 0.f;
  float4 c0 = Er[0], c1 = Er[1], c2 = Er[2], c3 = Er[3];
#pragma unroll 1
  for (int cc = 0; cc < 4; ++cc) {
    float4 n0, n1, n2, n3;
    if (cc < 3) { n0 = Er[cc * 4 + 4]; n1 = Er[cc * 4 + 5];
                  n2 = Er[cc * 4 + 6]; n3 = Er[cc * 4 + 7]; }
    float ev[16] = {c0.x, c0.y, c0.z, c0.w, c1.x, c1.y, c1.z, c1.w,
                    c2.x, c2.y, c2.z, c2.w, c3.x, c3.y, c3.z, c3.w};
#pragma unroll
    for (int k2i = 0; k2i < 16; ++k2i) {
      const float4* Wr = reinterpret_cast<const float4*>(
          W + ((size_t)(cc * 16 + k2i)) * 64);
      float ek = ev[k2i];
#pragma unroll
      for (int j4 = 0; j4 < 16; ++j4) {
        float4 w = Wr[j4];
        y[j4 * 4 + 0] = fmaf(ek, w.x, y[j4 * 4 + 0]);
        y[j4 * 4 + 1] = fmaf(ek, w.y, y[j4 * 4 + 1]);
        y[j4 * 4 + 2] = fmaf(ek, w.z, y[j4 * 4 + 2]);
        y[j4 * 4 + 3] = fmaf(ek, w.w, y[j4 * 4 + 3]);
      }
    }
    c0 = n0; c1 = n1; c2 = n2; c3 = n3;
  }
  const float4* B4 = reinterpret_cast<const float4*>(bias);
#pragma unroll
  for (int j4 = 0; j4 < 16; ++j4) {
    float4 bb = B4[j4];
    float bv[4] = {bb.x, bb.y, bb.z, bb.w};
#pragma unroll
    for (int t = 0; t < 4; ++t) y[j4 * 4 + t] = __fadd_rn(y[j4 * 4 + t], bv[t]);
  }
  // ss butterfly-replica tree (xor 32,16,8,4,2,1)
  float S1[32];
#pragma unroll
  for (int i = 0; i < 32; ++i)
    S1[i] = __fadd_rn(__fmul_rn(y[i], y[i]), __fmul_rn(y[i + 32], y[i + 32]));
#pragma unroll
  for (int i = 0; i < 16; ++i) S1[i] = __fadd_rn(S1[i], S1[i + 16]);
#pragma unroll
  for (int i = 0; i < 8; ++i)  S1[i] = __fadd_rn(S1[i], S1[i + 8]);
#pragma unroll
  for (int i = 0; i < 4; ++i)  S1[i] = __fadd_rn(S1[i], S1[i + 4]);
#pragma unroll
  for (int i = 0; i < 2; ++i)  S1[i] = __fadd_rn(S1[i], S1[i + 2]);
  float ss = __fadd_rn(S1[0], S1[1]);
  float denom = fmaxf(sqrtf(ss), EPS_NORM);
#pragma unroll
  for (int j = 0; j < 64; ++j) yn[j] = y[j] / denom;
}

// ---- unified transform: T1 = l2n(E@W1+b1) for ALL entities; T2c for cands ---
__global__ __launch_bounds__(256) void k_tx(
    const float* __restrict__ E, const int* __restrict__ allc,
    const float* __restrict__ W1, const float* __restrict__ b1,
    const float* __restrict__ W2, const float* __restrict__ b2,
    float* __restrict__ T1, float* __restrict__ T2c,
    int nEnt /*200000*/, int nCand /*6400*/) {
  int tid = threadIdx.x, wv = tid >> 6, lane = tid & 63;
  int w = rfl(blockIdx.x * 4 + wv);
  int wEnt = nEnt >> 6;                 // 3125 waves for T1
  int wTot = wEnt + (nCand >> 6);       // + 100 waves for T2c
  if (w >= wTot) return;
  const float *W, *bias; float* dst; int srow, drow;
  if (w < wEnt) { drow = w * 64 + lane; srow = drow; W = W1; bias = b1; dst = T1; }
  else { drow = (w - wEnt) * 64 + lane; srow = allc[drow]; W = W2; bias = b2; dst = T2c; }
  const float4* Er = reinterpret_cast<const float4*>(E + (size_t)srow * 64);
  float yn[64];
  transform_row(Er, W, bias, yn);
  float4* D4 = reinterpret_cast<float4*>(dst + (size_t)drow * 64);
#pragma unroll
  for (int j4 = 0; j4 < 16; ++j4)
    D4[j4] = make_float4(yn[4 * j4], yn[4 * j4 + 1], yn[4 * j4 + 2], yn[4 * j4 + 3]);
}

// ------------- generic 64x64 row transform (fallback path for T2c) -----------
__global__ __launch_bounds__(256) void k_transform64(
    const float* __restrict__ src, const int* __restrict__ gidx,
    const float* __restrict__ W, const float* __restrict__ bias,
    float* __restrict__ out, int nrows) {
  __shared__ float Wl[4096];
  for (int i = threadIdx.x; i < 4096; i += 256) Wl[i] = W[i];
  __syncthreads();
  int wid = threadIdx.x >> 6, lane = threadIdx.x & 63;
  int row = rfl(blockIdx.x * 4 + wid);
  if (row >= nrows) return;
  int srow = rfl(gidx ? gidx[row] : row);
  const float* er = src + (size_t)srow * 64;
  float y = 0.f;
#pragma unroll
  for (int k = 0; k < 64; ++k) y = fmaf(er[k], Wl[k * 64 + lane], y);
  y += bias[lane];
  float ss = y * y;
#pragma unroll
  for (int off = 32; off; off >>= 1) ss += __shfl_xor(ss, off);
  float yn = y / fmaxf(sqrtf(ss), EPS_NORM);
  out[(size_t)row * 64 + lane] = yn;
}

// ---------------- ui_e = l2norm(concat(U[users], Iemb) @ uiW + uib) ----------
__global__ __launch_bounds__(256) void k_ui(
    const float* __restrict__ U, const int* __restrict__ users,
    const float* __restrict__ Iemb, const float* __restrict__ W,
    const float* __restrict__ bias, float* __restrict__ out, int B) {
  __shared__ float Wl[8192];
  for (int i = threadIdx.x; i < 8192; i += 256) Wl[i] = W[i];
  __syncthreads();
  int wid = threadIdx.x >> 6, lane = threadIdx.x & 63;
  int b = rfl(blockIdx.x * 4 + wid);
  if (b >= B) return;
  int usr = rfl(users[b]);
  const float* ur = U + (size_t)usr * 64;
  const float* ir = Iemb + (size_t)b * 64;
  float y = 0.f;
#pragma unroll
  for (int k = 0; k < 64; ++k) y = fmaf(ur[k], Wl[k * 64 + lane], y);
#pragma unroll
  for (int k = 0; k < 64; ++k) y = fmaf(ir[k], Wl[(64 + k) * 64 + lane], y);
  y += bias[lane];
  float ss = y * y;
#pragma unroll
  for (int off = 32; off; off >>= 1) ss += __shfl_xor(ss, off);
  float yn = y / fmaxf(sqrtf(ss), EPS_NORM);
  out[(size_t)b * 64 + lane] = yn;
}

// ------------------ step1 tail (softmax + top4), shared ----------------------
__device__ __forceinline__ void score1_tail(
    float s, int lane, int b, int item, int nb,
    const int* __restrict__ nrel,
    float* __restrict__ out0, float* __restrict__ ap1_out,
    int* __restrict__ s1_idx, int* __restrict__ s1_rel, int* __restrict__ s1_ent,
    float* __restrict__ lmp1) {
  float m = s;
#pragma unroll
  for (int off = 32; off; off >>= 1) m = fmaxf(m, __shfl_xor(m, off));
  float ex = expf(s - m);
  float sum = ex;
#pragma unroll
  for (int off = 32; off; off >>= 1) sum += __shfl_xor(sum, off);
  float p = ex / sum;
  int rank = 0;
  for (int k2 = 0; k2 < 64; ++k2) {
    float pv = __shfl(p, k2);
    rank += (pv > p || (pv == p && k2 < lane)) ? 1 : 0;
  }
  float acc = 0.f;
#pragma unroll
  for (int rr = 0; rr < 4; ++rr) {
    unsigned long long msk = __ballot(rank == rr);
    int src = __ffsll(msk) - 1;
    acc += __shfl(p, src);
  }
  float lm = logf(acc * 0.25f);
  if (lane == 0) { ap1_out[b] = lm; lmp1[b] = lm; }
  if (rank < 4) {
    s1_idx[b * 4 + rank] = lane;
    s1_ent[b * 4 + rank] = nb;
    s1_rel[b * 4 + rank] = nrel[(size_t)item * 64 + lane];
    out0[(size_t)item * 64 + lane] = 0.0f;
  }
}

// ---------- step1 (path A): gather T1 rows + in-register dot + tail ----------
__global__ __launch_bounds__(256) void k_score1g(
    const int* __restrict__ items, const int* __restrict__ kg,
    const int* __restrict__ nrel, const float* __restrict__ T1,
    const float* __restrict__ uiE,
    float* __restrict__ out0, float* __restrict__ ap1_out,
    int* __restrict__ s1_idx, int* __restrict__ s1_rel, int* __restrict__ s1_ent,
    float* __restrict__ lmp1) {
  int tid = threadIdx.x, wv = tid >> 6, lane = tid & 63;
  int b = rfl(blockIdx.x * 4 + wv);
  int item = rfl(items[b]);
  int nb = kg[(size_t)item * 64 + lane];
  const float4* R = reinterpret_cast<const float4*>(T1 + (size_t)nb * 64);
  float yn[64];
#pragma unroll
  for (int j4 = 0; j4 < 16; ++j4) {
    float4 v = R[j4];
    yn[4 * j4] = v.x; yn[4 * j4 + 1] = v.y; yn[4 * j4 + 2] = v.z; yn[4 * j4 + 3] = v.w;
  }
  const float4* Ur = reinterpret_cast<const float4*>(uiE + (size_t)b * 64);
  float D[32];
#pragma unroll
  for (int i4 = 0; i4 < 8; ++i4) {
    float4 ua = Ur[i4], ub = Ur[i4 + 8];
    float uav[4] = {ua.x, ua.y, ua.z, ua.w};
    float ubv[4] = {ub.x, ub.y, ub.z, ub.w};
#pragma unroll
    for (int t = 0; t < 4; ++t) {
      int i = i4 * 4 + t;
      D[i] = __fadd_rn(__fmul_rn(yn[i], uav[t]), __fmul_rn(yn[i + 32], ubv[t]));
    }
  }
#pragma unroll
  for (int i = 0; i < 16; ++i) D[i] = __fadd_rn(D[i], D[i + 16]);
#pragma unroll
  for (int i = 0; i < 8; ++i)  D[i] = __fadd_rn(D[i], D[i + 8]);
#pragma unroll
  for (int i = 0; i < 4; ++i)  D[i] = __fadd_rn(D[i], D[i + 4]);
#pragma unroll
  for (int i = 0; i < 2; ++i)  D[i] = __fadd_rn(D[i], D[i + 2]);
  float s = __fadd_rn(D[0], D[1]);
  score1_tail(s, lane, b, item, nb, nrel, out0, ap1_out, s1_idx, s1_rel, s1_ent, lmp1);
}

// ---------- step1 (path B fallback): fused transform + dot + tail ------------
__global__ __launch_bounds__(256) void k_score1(
    const int* __restrict__ items, const int* __restrict__ kg,
    const int* __restrict__ nrel, const float* __restrict__ E,
    const float* __restrict__ W1, const float* __restrict__ b1,
    const float* __restrict__ uiE,
    float* __restrict__ out0, float* __restrict__ ap1_out,
    int* __restrict__ s1_idx, int* __restrict__ s1_rel, int* __restrict__ s1_ent,
    float* __restrict__ lmp1) {
  int tid = threadIdx.x, wv = tid >> 6, lane = tid & 63;
  int b = rfl(blockIdx.x * 4 + wv);
  int item = rfl(items[b]);
  int nb = kg[(size_t)item * 64 + lane];
  const float4* Er = reinterpret_cast<const float4*>(E + (size_t)nb * 64);
  float yn[64];
  transform_row(Er, W1, b1, yn);
  const float4* Ur = reinterpret_cast<const float4*>(uiE + (size_t)b * 64);
  float D[32];
#pragma unroll
  for (int i4 = 0; i4 < 8; ++i4) {
    float4 ua = Ur[i4], ub = Ur[i4 + 8];
    float uav[4] = {ua.x, ua.y, ua.z, ua.w};
    float ubv[4] = {ub.x, ub.y, ub.z, ub.w};
#pragma unroll
    for (int t = 0; t < 4; ++t) {
      int i = i4 * 4 + t;
      D[i] = __fadd_rn(__fmul_rn(yn[i], uav[t]), __fmul_rn(yn[i + 32], ubv[t]));
    }
  }
#pragma unroll
  for (int i = 0; i < 16; ++i) D[i] = __fadd_rn(D[i], D[i + 16]);
#pragma unroll
  for (int i = 0; i < 8; ++i)  D[i] = __fadd_rn(D[i], D[i + 8]);
#pragma unroll
  for (int i = 0; i < 4; ++i)  D[i] = __fadd_rn(D[i], D[i + 4]);
#pragma unroll
  for (int i = 0; i < 2; ++i)  D[i] = __fadd_rn(D[i], D[i + 2]);
  float s = __fadd_rn(D[0], D[1]);
  score1_tail(s, lane, b, item, nb, nrel, out0, ap1_out, s1_idx, s1_rel, s1_ent, lmp1);
}

// ------- step2a: raw-embedding candidate scores + stable top-32 --------------
__global__ __launch_bounds__(256) void k_score2(
    const int* __restrict__ users, const int* __restrict__ s1_rel,
    const float* __restrict__ U, const float* __restrict__ E,
    const int* __restrict__ allc, int* __restrict__ kept, int N) {
  int wid = threadIdx.x >> 6, lane = threadIdx.x & 63;
  int n = rfl(blockIdx.x * 4 + wid);
  if (n >= N) return;
  int b = n >> 2;
  int rel = rfl(s1_rel[n]);
  int usr = rfl(users[b]);
  int ent = allc[rel * 64 + lane];
  const float* ur = U + (size_t)usr * 64;        // wave-uniform row
  const float4* e4 = reinterpret_cast<const float4*>(E + (size_t)ent * 64);
  float s = 0.f;
#pragma unroll
  for (int j4 = 0; j4 < 16; ++j4) {
    float4 t = e4[j4];
    s = fmaf(ur[4 * j4 + 0], t.x, s);
    s = fmaf(ur[4 * j4 + 1], t.y, s);
    s = fmaf(ur[4 * j4 + 2], t.z, s);
    s = fmaf(ur[4 * j4 + 3], t.w, s);
  }
  int rank = 0;
  for (int k2 = 0; k2 < 64; ++k2) {
    float sv = __shfl(s, k2);
    rank += (sv > s || (sv == s && k2 < lane)) ? 1 : 0;
  }
  if (rank < 32) kept[n * 32 + rank] = (lane << 18) | ent;  // pack (col, entity)
}

// ------- step2b shared body: s2, log_softmax, gumbel sample, scatter ---------
__device__ __forceinline__ void sample_body(
    float q, int n, int b, int lane,
    const int* __restrict__ items, const int* __restrict__ s1_idx,
    int rel, const float* __restrict__ T2c, const int* __restrict__ kept,
    float* __restrict__ p2, int* __restrict__ wkg2) {
  int m = lane & 31;
  int pk = kept[n * 32 + m];
  int c = pk >> 18;
  int ent = pk & 0x3FFFF;
  const float4* c4 = reinterpret_cast<const float4*>(T2c + ((size_t)rel * 64 + c) * 64);
  float s = 0.f;
#pragma unroll
  for (int j4 = 0; j4 < 16; ++j4) {
    float4 t = c4[j4];
    s = fmaf(__shfl(q, 4 * j4 + 0), t.x, s);
    s = fmaf(__shfl(q, 4 * j4 + 1), t.y, s);
    s = fmaf(__shfl(q, 4 * j4 + 2), t.z, s);
    s = fmaf(__shfl(q, 4 * j4 + 3), t.w, s);
  }
  float mx = s;
#pragma unroll
  for (int off = 1; off < 32; off <<= 1) mx = fmaxf(mx, __shfl_xor(mx, off));
  float shv = s - mx;
  float se = expf(shv);
  float sum = se;
#pragma unroll
  for (int off = 1; off < 32; off <<= 1) sum += __shfl_xor(sum, off);
  float logp = shv - logf(sum);
  uint32_t h0, h1;
  threefry2x32(0u, 42u, 0u, (uint32_t)(n * 32 + m), h0, h1);
  uint32_t bits = h0 ^ h1;
  float u0 = __uint_as_float((bits >> 9) | 0x3F800000u) - 1.0f;
  float uu = fmaxf(u0, F32_TINY);
  float g = -logf(-logf(uu));
  float z = g + logp;
  float bz = z; int bm = m;
#pragma unroll
  for (int off = 1; off < 32; off <<= 1) {
    float oz = __shfl_xor(bz, off);
    int om = __shfl_xor(bm, off);
    if (oz > bz || (oz == bz && om < bm)) { bz = oz; bm = om; }
  }
  if (lane == bm) {
    p2[n] = expf(logp);
    int col = s1_idx[n];
    int item = items[b];
    atomicMax(&wkg2[(size_t)item * 64 + col], ((b + 1) << 18) | ent);
  }
}

// ---------- step2b (path A): T1-row read, no transform -----------------------
__global__ __launch_bounds__(256) void k_sample2(
    const int* __restrict__ items,
    const int* __restrict__ s1_idx, const int* __restrict__ s1_rel,
    const int* __restrict__ s1_ent, const float* __restrict__ T1,
    const float* __restrict__ T2c, const float* __restrict__ uiE,
    const int* __restrict__ kept,
    float* __restrict__ p2, int* __restrict__ wkg2, int N) {
  int tid = threadIdx.x, wid = tid >> 6, lane = tid & 63;
  int n = rfl(blockIdx.x * 4 + wid);
  if (n >= N) return;
  int b = n >> 2;
  int rel = rfl(s1_rel[n]);
  int repl = rfl(s1_ent[n]);
  float q = uiE[(size_t)b * 64 + lane] * T1[(size_t)repl * 64 + lane];
  sample_body(q, n, b, lane, items, s1_idx, rel, T2c, kept, p2, wkg2);
}

// ---------- step2b (path B fallback): recompute transform --------------------
__global__ __launch_bounds__(256) void k_sample(
    const int* __restrict__ items,
    const int* __restrict__ s1_idx, const int* __restrict__ s1_rel,
    const int* __restrict__ s1_ent,
    const float* __restrict__ E, const float* __restrict__ W1,
    const float* __restrict__ b1, const float* __restrict__ T2c,
    const float* __restrict__ uiE, const int* __restrict__ kept,
    float* __restrict__ p2, int* __restrict__ wkg2, int N) {
  __shared__ float Wl[4096];
  int tid = threadIdx.x;
  for (int i = tid; i < 4096; i += 256) Wl[i] = W1[i];
  __syncthreads();
  int wid = tid >> 6, lane = tid & 63;
  int n = rfl(blockIdx.x * 4 + wid);
  if (n >= N) return;
  int b = n >> 2;
  int rel = rfl(s1_rel[n]);
  int repl = rfl(s1_ent[n]);
  const float* er = E + (size_t)repl * 64;
  float y = 0.f;
#pragma unroll
  for (int k2 = 0; k2 < 64; ++k2) y = fmaf(er[k2], Wl[k2 * 64 + lane], y);
  y += b1[lane];
  float ss = y * y;
#pragma unroll
  for (int off = 32; off; off >>= 1) ss += __shfl_xor(ss, off);
  float yn = y / fmaxf(sqrtf(ss), EPS_NORM);
  float q = uiE[(size_t)b * 64 + lane] * yn;
  sample_body(q, n, b, lane, items, s1_idx, rel, T2c, kept, p2, wkg2);
}

// ---------------- finalize cf_kg2 and ap2 (merged) ---------------------------
__global__ __launch_bounds__(256) void k_fin(const int* __restrict__ wkg2,
                                             const float* __restrict__ p2,
                                             const float* __restrict__ lmp1,
                                             float* __restrict__ out2,
                                             float* __restrict__ out3,
                                             int n, int B) {
  int i = blockIdx.x * 256 + threadIdx.x;
  if (i < n) out2[i] = (float)(wkg2[i] & 0x3FFFF);
  if (i < B) {
    float a = ((p2[i * 4] + p2[i * 4 + 1]) + p2[i * 4 + 2]) + p2[i * 4 + 3];
    out3[i] = lmp1[i] + logf(a * 0.25f);
  }
}

// -----------------------------------------------------------------------------
extern "C" void kernel_launch(void* const* d_in, const int* in_sizes, int n_in,
                              void* d_out, int out_size, void* d_ws, size_t ws_size,
                              hipStream_t stream) {
  const int*   users = (const int*)d_in[0];
  const int*   items = (const int*)d_in[1];
  const int*   kg    = (const int*)d_in[2];
  const int*   allc  = (const int*)d_in[3];
  const int*   nrel  = (const int*)d_in[4];
  const float* U     = (const float*)d_in[5];
  const float* E     = (const float*)d_in[6];
  const float* Iemb  = (const float*)d_in[7];
  const float* uiW   = (const float*)d_in[8];
  const float* uib   = (const float*)d_in[9];
  const float* e1W   = (const float*)d_in[10];
  const float* e1b   = (const float*)d_in[11];
  const float* e2W   = (const float*)d_in[12];
  const float* e2b   = (const float*)d_in[13];

  const int B = 4096, NCELL = 3200000, NCAND = 6400, NR4 = 16384, NENT = 200000;

  float* out0    = (float*)d_out;        // cf_kg1 [3.2M]
  float* out_ap1 = out0 + NCELL;         // ap1    [4096]
  float* out2    = out_ap1 + B;          // cf_kg2 [3.2M]
  float* out_ap2 = out2 + NCELL;         // ap2    [4096]

  float* T2c  = (float*)d_ws;            // 409,600 f
  float* uiE  = T2c + 409600;            // 262,144 f
  int*   wkg2 = (int*)(uiE + 262144);    // 3,200,000 i
  int*   s1i  = wkg2 + NCELL;            // 16384
  int*   s1r  = s1i + NR4;               // 16384
  int*   s1e  = s1r + NR4;               // 16384
  int*   kept = s1e + NR4;               // 524,288
  float* p2   = (float*)(kept + 524288); // 16384
  float* lmp1 = p2 + NR4;                // 4096
  float* T1   = lmp1 + B;                // 12,800,000 f (51.2 MB), path A only
  const size_t WS_NEED = ((size_t)(T1 + (size_t)NENT * 64) - (size_t)d_ws);
  const bool pathA = ws_size >= WS_NEED;

  k_init<<<(NCELL + 255) / 256, 256, 0, stream>>>(kg, out0, wkg2, NCELL);
  k_ui<<<(B + 3) / 4, 256, 0, stream>>>(U, users, Iemb, uiW, uib, uiE, B);
  if (pathA) {
    int wTot = (NENT >> 6) + (NCAND >> 6);            // 3225 waves
    k_tx<<<(wTot + 3) / 4, 256, 0, stream>>>(E, allc, e1W, e1b, e2W, e2b,
                                             T1, T2c, NENT, NCAND);
    k_score1g<<<B / 4, 256, 0, stream>>>(items, kg, nrel, T1, uiE,
                                         out0, out_ap1, s1i, s1r, s1e, lmp1);
    k_score2<<<(NR4 + 3) / 4, 256, 0, stream>>>(users, s1r, U, E, allc, kept, NR4);
    k_sample2<<<(NR4 + 3) / 4, 256, 0, stream>>>(items, s1i, s1r, s1e, T1, T2c,
                                                 uiE, kept, p2, wkg2, NR4);
  } else {
    k_transform64<<<(NCAND + 3) / 4, 256, 0, stream>>>(E, allc, e2W, e2b, T2c, NCAND);
    k_score1<<<B / 4, 256, 0, stream>>>(items, kg, nrel, E, e1W, e1b, uiE,
                                        out0, out_ap1, s1i, s1r, s1e, lmp1);
    k_score2<<<(NR4 + 3) / 4, 256, 0, stream>>>(users, s1r, U, E, allc, kept, NR4);
    k_sample<<<(NR4 + 3) / 4, 256, 0, stream>>>(items, s1i, s1r, s1e, E, e1W, e1b,
                                                T2c, uiE, kept, p2, wkg2, NR4);
  }
  k_fin<<<(NCELL + 255) / 256, 256, 0, stream>>>(wkg2, p2, lmp1, out2, out_ap2,
                                                 NCELL, B);
}